// Round 5
// baseline (115.053 us; speedup 1.0000x reference)
//
#include <hip/hip_runtime.h>
#include <hip/hip_bf16.h>
#include <math.h>

// Problem constants (from setup_inputs):
#define NN 1024
#define TT 128
#define SS 6
#define FF 2
#define HH 256
#define AA 18
#define MM 512
#define KH 20
#define BB (NN*SS)        // 6144
#define RR (FF*BB)        // 12288

#define SCL_RZ (-1.44269504089f)      // -log2(e)
#define SCL_N  (-2.88539008178f)      // -2*log2(e)
#define TBL_STRIDE 784                // 768 + 16 pad f32 -> odd-bank shift per action row

typedef __bf16 bf16x8 __attribute__((ext_vector_type(8)));
typedef float f32x4 __attribute__((ext_vector_type(4)));

__device__ __forceinline__ f32x4 mfma16(bf16x8 a, bf16x8 b, f32x4 c) {
    return __builtin_amdgcn_mfma_f32_16x16x32_bf16(a, b, c, 0, 0, 0);
}
__device__ __forceinline__ unsigned short f2b(float f) {
    return __builtin_bit_cast(unsigned short, __float2bfloat16(f));
}
__device__ __forceinline__ float b2f(unsigned short u) {
    return __builtin_bit_cast(float, (unsigned)u << 16);
}
__device__ __forceinline__ float rcp_f(float x)  { return __builtin_amdgcn_rcpf(x); }
__device__ __forceinline__ float exp2_f(float x) { return __builtin_amdgcn_exp2f(x); }

// ---- ws layout (bytes) ----
#define OFF_ACT   0UL                 // BB*20 int = 491,520
#define OFF_HPRED 491520UL            // RR*HH bf16 = 6,291,456
#define OFF_WHH   6782976UL           // 768*256 bf16 (pre-scaled) = 393,216
#define OFF_W1T   7176192UL           // 512*256 bf16 = 262,144
#define OFF_W2T   7438336UL           // 512*512 bf16 = 524,288
#define OFF_W3T   7962624UL           // 256*512 bf16 = 262,144
#define OFF_TBL   8224768UL           // 19*784 f32 = 59,584
#define OFF_PART  8284352UL           // 256*3 f32 = 3,072

// Prep: scaled bf16 W_hh, transposed MLP weights, gi lookup table, action table.
__global__ void k_prep(const float* __restrict__ Whh, const float* __restrict__ W1,
                       const float* __restrict__ W2, const float* __restrict__ W3,
                       const float* __restrict__ Wih, const float* __restrict__ bih,
                       const float* __restrict__ bhh,
                       const int* __restrict__ actions, const int* __restrict__ ts,
                       unsigned short* whh_s, unsigned short* w1t, unsigned short* w2t,
                       unsigned short* w3t, float* tbl, int* act) {
    int idx = blockIdx.x * 256 + threadIdx.x;
    if (idx < 196608) {   // W_hh, pre-scaled per gate
        int wrow = idx >> 8;
        float scl = (wrow < 512) ? SCL_RZ : SCL_N;
        whh_s[idx] = f2b(Whh[idx] * scl);
        return;
    }
    idx -= 196608;
    if (idx < 131072) { int m = idx >> 8, k = idx & 255; w1t[idx] = f2b(W1[k * MM + m]); return; }
    idx -= 131072;
    if (idx < 262144) { int m = idx >> 9, k = idx & 511; w2t[idx] = f2b(W2[k * MM + m]); return; }
    idx -= 262144;
    if (idx < 131072) { int c = idx >> 9, k = idx & 511; w3t[idx] = f2b(W3[k * HH + c]); return; }
    idx -= 131072;
    if (idx < 19 * TBL_STRIDE) {   // tbl[a][g*256+j] = scl_g*(Wih[g*256+j][a] + bih + (g<2)*bhh)
        int a = idx / TBL_STRIDE, rem = idx - a * TBL_STRIDE;
        float v = 0.f;
        if (rem < 768) {
            int g = rem >> 8;
            float scl = (g < 2) ? SCL_RZ : SCL_N;
            float w = (a < AA) ? Wih[rem * AA + a] : 0.f;
            v = scl * (w + bih[rem] + ((g < 2) ? bhh[rem] : 0.f));
        }
        tbl[idx] = v;
        return;
    }
    idx -= 19 * TBL_STRIDE;
    if (idx < BB * KH) {   // act[b][k]: action index, AA for padded steps
        int b = idx / KH, k = idx - b * KH;
        int n = b / SS, s = b - n * SS;
        int tt = ts[s] + k;
        act[idx] = (tt < TT - 1) ? actions[n * TT + tt] : AA;
    }
}

// Weights-stationary GRU: 256 blocks x 512 thr; block owns 24 rows (pad to 32).
// W_hh register-resident; double-buffered htile -> ONE barrier per step
// (epilogue VALU of leading wave overlaps MFMA of trailing wave on the SIMD).
__global__ void __launch_bounds__(512, 2)
k_gru_all(const unsigned short* __restrict__ whh_s, const float* __restrict__ tblg,
          const float* __restrict__ bhh, const int* __restrict__ actg,
          const int* __restrict__ us, const int* __restrict__ ts,
          const float* __restrict__ b_t, unsigned short* __restrict__ hpred) {
    __shared__ float tbl[19 * TBL_STRIDE];          // 59.6 KB
    __shared__ unsigned short htile[2][32][264];    // 33.8 KB double buffer (+8 pad)
    __shared__ int act_l[24][KH];                   // 1.9 KB

    int tid = threadIdx.x, wave = tid >> 6, lane = tid & 63;
    int l15 = lane & 15, grp = lane >> 4, lk8 = grp << 3, r4 = grp << 2;
    int rb = blockIdx.x * 24;
    int u0 = us[0], u1 = us[1];
    int kmax = u0 > u1 ? u0 : u1;

    // stage lookup table + actions
    for (int i = tid; i < 19 * TBL_STRIDE / 4; i += 512)
        reinterpret_cast<float4*>(tbl)[i] = reinterpret_cast<const float4*>(tblg)[i];
    if (tid < 24 * KH) {
        int r = tid / KH, k2 = tid - r * KH;
        act_l[r][k2] = actg[(rb + r) * KH + k2];
    }

    // htile init: buf0 rows<24 = bf16(h0); pad rows (and buf1) zero
    for (int i = tid; i < 2 * 32 * 32; i += 512) {
        int buf = i >> 10, rem = i & 1023, row = rem >> 5, c8 = (rem & 31) << 3;
        uint4 pk = {0u, 0u, 0u, 0u};
        if (buf == 0 && row < 24) {
            int b = rb + row;
            int n = b / SS, s = b - n * SS;
            const float* src = &b_t[(size_t)(n * TT + ts[s]) * HH + c8];
            pk.x = f2b(src[0]) | ((unsigned)f2b(src[1]) << 16);
            pk.y = f2b(src[2]) | ((unsigned)f2b(src[3]) << 16);
            pk.z = f2b(src[4]) | ((unsigned)f2b(src[5]) << 16);
            pk.w = f2b(src[6]) | ((unsigned)f2b(src[7]) << 16);
        }
        *reinterpret_cast<uint4*>(&htile[buf][row][c8]) = pk;
    }

    // weights -> registers: wave owns j-window [wave*32,+32), 3 gates (96 W rows).
    bf16x8 wr[6][8];
#pragma unroll
    for (int ct = 0; ct < 6; ++ct) {
        int wrow = (ct >> 1) * 256 + wave * 32 + (ct & 1) * 16 + l15;
        const unsigned short* base = &whh_s[(size_t)wrow * HH];
#pragma unroll
        for (int kk = 0; kk < 8; ++kk)
            wr[ct][kk] = *reinterpret_cast<const bf16x8*>(&base[kk * 32 + lk8]);
    }
    float bhn[2];
#pragma unroll
    for (int cj = 0; cj < 2; ++cj) bhn[cj] = SCL_N * bhh[512 + wave * 32 + cj * 16 + l15];
    __syncthreads();

    int cur = 0;
    for (int ki = 0; ki <= kmax; ++ki) {
        int nxt = cur ^ 1;
#pragma unroll
        for (int rt = 0; rt < 2; ++rt) {
            f32x4 aR[2] = {}, aZ[2] = {}, aN[2] = {};
#pragma unroll
            for (int kk = 0; kk < 8; ++kk) {
                bf16x8 ah = *reinterpret_cast<const bf16x8*>(&htile[cur][rt * 16 + l15][kk * 32 + lk8]);
                aR[0] = mfma16(ah, wr[0][kk], aR[0]);
                aR[1] = mfma16(ah, wr[1][kk], aR[1]);
                aZ[0] = mfma16(ah, wr[2][kk], aZ[0]);
                aZ[1] = mfma16(ah, wr[3][kk], aZ[1]);
                aN[0] = mfma16(ah, wr[4][kk], aN[0]);
                aN[1] = mfma16(ah, wr[5][kk], aN[1]);
            }
            // epilogue for this row-tile (rows >= 24 are pad -> skip)
#pragma unroll
            for (int cj = 0; cj < 2; ++cj) {
                int j2 = wave * 32 + cj * 16 + l15;
                float bhnv = bhn[cj];
#pragma unroll
                for (int reg = 0; reg < 4; ++reg) {
                    int rowl = rt * 16 + r4 + reg;
                    if (rt == 0 || rowl < 24) {
                        const float* tb = &tbl[act_l[rowl][ki] * TBL_STRIDE];
                        float r = rcp_f(1.f + exp2_f(aR[cj][reg] + tb[j2]));
                        float z = rcp_f(1.f + exp2_f(aZ[cj][reg] + tb[256 + j2]));
                        float ghn = aN[cj][reg] + bhnv;
                        float nv = 2.f * rcp_f(1.f + exp2_f(tb[512 + j2] + r * ghn)) - 1.f;
                        float h = b2f(htile[cur][rowl][j2]);
                        float hn2 = nv + z * (h - nv);
                        unsigned short hbv = f2b(hn2);
                        htile[nxt][rowl][j2] = hbv;
                        if (ki == u0) hpred[(size_t)(rb + rowl) * HH + j2] = hbv;
                        if (ki == u1) hpred[(size_t)(BB + rb + rowl) * HH + j2] = hbv;
                    }
                }
            }
        }
        __syncthreads();   // nxt fully written; cur fully read
        cur = nxt;
    }
}

// Fused 3-layer MLP + loss: 256 blocks x 48 rows. pred never leaves registers.
// loss row needs only {sum p^2, sum z^2, sum p.z}: per-wave shfl partials + LDS reduce.
__device__ __forceinline__ int xsw(int row, int chunk) {
    return (row << 9) + ((chunk ^ (row & 7)) << 3);   // ushort index, 16B granules
}

__global__ void __launch_bounds__(512, 4)
k_mlp_loss(const unsigned short* __restrict__ hpred, const unsigned short* __restrict__ w1t,
           const unsigned short* __restrict__ w2t, const unsigned short* __restrict__ w3t,
           const float* __restrict__ b1, const float* __restrict__ b2,
           const float* __restrict__ b3, const float* __restrict__ z_t,
           const float* __restrict__ dones, const int* __restrict__ ts,
           const int* __restrict__ us, float* __restrict__ part) {
    __shared__ unsigned short xs[48 * 512];   // 49.2 KB
    __shared__ unsigned short zs[48 * 256];   // 24.6 KB (bf16 targets)
    __shared__ float rstat[48][8][3];         // 4.6 KB
    __shared__ float vmask[48];

    int tid = threadIdx.x, wave = tid >> 6, lane = tid & 63;
    int l15 = lane & 15, grp = lane >> 4, lk8 = grp << 3, r4 = grp << 2;
    int rb = blockIdx.x * 48;

    // per-row validity mask
    if (tid < 48) {
        int rg = rb + tid;
        int f = rg >= BB ? 1 : 0;
        int b = rg - f * BB;
        int n = b / SS, s = b - n * SS;
        int t = ts[s], u = us[f];
        float m = (t + u < TT - 1) ? 1.f : 0.f;
        if (m > 0.f) for (int j = 0; j <= u; ++j) m *= (1.f - dones[n * TT + t + j]);
        vmask[tid] = (m > 0.f) ? 1.f : 0.f;
    }
    // stage z targets -> bf16 LDS (zero for out-of-range rows)
    for (int i = tid; i < 48 * 64; i += 512) {
        int row = i >> 6, c4 = (i & 63) << 2;
        int rg = rb + row;
        int f = rg >= BB ? 1 : 0;
        int b = rg - f * BB;
        int n = b / SS, s = b - n * SS;
        int t = ts[s], u = us[f];
        uint2 pk = {0u, 0u};
        if (t + u < TT - 1) {
            float4 v = *reinterpret_cast<const float4*>(&z_t[(size_t)(n * TT + 1 + t + u) * HH + c4]);
            pk.x = f2b(v.x) | ((unsigned)f2b(v.y) << 16);
            pk.y = f2b(v.z) | ((unsigned)f2b(v.w) << 16);
        }
        *reinterpret_cast<uint2*>(&zs[row * 256 + c4]) = pk;
    }

    // Layer 1: x1 = relu(hpred @ W1 + b1), K=256
    {
        f32x4 acc[3][4] = {};
        for (int kk = 0; kk < 8; ++kk) {
            int k0 = kk * 32 + lk8;
            bf16x8 av[3];
#pragma unroll
            for (int rt = 0; rt < 3; ++rt)
                av[rt] = *reinterpret_cast<const bf16x8*>(&hpred[(size_t)(rb + rt * 16 + l15) * HH + k0]);
#pragma unroll
            for (int ct = 0; ct < 4; ++ct) {
                int col = wave * 64 + ct * 16 + l15;
                bf16x8 bv = *reinterpret_cast<const bf16x8*>(&w1t[(size_t)col * HH + k0]);
#pragma unroll
                for (int rt = 0; rt < 3; ++rt) acc[rt][ct] = mfma16(av[rt], bv, acc[rt][ct]);
            }
        }
#pragma unroll
        for (int ct = 0; ct < 4; ++ct) {
            int col = wave * 64 + ct * 16 + l15;
            float bb = b1[col];
#pragma unroll
            for (int rt = 0; rt < 3; ++rt)
#pragma unroll
                for (int reg = 0; reg < 4; ++reg)
                    xs[xsw(rt * 16 + r4 + reg, col >> 3) + (col & 7)] =
                        f2b(fmaxf(acc[rt][ct][reg] + bb, 0.f));
        }
    }
    __syncthreads();   // also covers zs/vmask staging

    // Layer 2: x2 = relu(x1 @ W2 + b2), K=512
    {
        f32x4 acc[3][4] = {};
        for (int kk = 0; kk < 16; ++kk) {
            bf16x8 av[3];
#pragma unroll
            for (int rt = 0; rt < 3; ++rt)
                av[rt] = *reinterpret_cast<const bf16x8*>(&xs[xsw(rt * 16 + l15, kk * 4 + grp)]);
#pragma unroll
            for (int ct = 0; ct < 4; ++ct) {
                int col = wave * 64 + ct * 16 + l15;
                bf16x8 bv = *reinterpret_cast<const bf16x8*>(&w2t[(size_t)col * MM + kk * 32 + lk8]);
#pragma unroll
                for (int rt = 0; rt < 3; ++rt) acc[rt][ct] = mfma16(av[rt], bv, acc[rt][ct]);
            }
        }
        __syncthreads();
#pragma unroll
        for (int ct = 0; ct < 4; ++ct) {
            int col = wave * 64 + ct * 16 + l15;
            float bb = b2[col];
#pragma unroll
            for (int rt = 0; rt < 3; ++rt)
#pragma unroll
                for (int reg = 0; reg < 4; ++reg)
                    xs[xsw(rt * 16 + r4 + reg, col >> 3) + (col & 7)] =
                        f2b(fmaxf(acc[rt][ct][reg] + bb, 0.f));
        }
    }
    __syncthreads();

    // Layer 3 + loss stats: wave owns 32 cols
    {
        f32x4 acc[3][2] = {};
        for (int kk = 0; kk < 16; ++kk) {
            bf16x8 av[3];
#pragma unroll
            for (int rt = 0; rt < 3; ++rt)
                av[rt] = *reinterpret_cast<const bf16x8*>(&xs[xsw(rt * 16 + l15, kk * 4 + grp)]);
#pragma unroll
            for (int ct = 0; ct < 2; ++ct) {
                int col = wave * 32 + ct * 16 + l15;
                bf16x8 bv = *reinterpret_cast<const bf16x8*>(&w3t[(size_t)col * MM + kk * 32 + lk8]);
#pragma unroll
                for (int rt = 0; rt < 3; ++rt) acc[rt][ct] = mfma16(av[rt], bv, acc[rt][ct]);
            }
        }
        float b3c0 = b3[wave * 32 + l15];
        float b3c1 = b3[wave * 32 + 16 + l15];
#pragma unroll
        for (int rt = 0; rt < 3; ++rt)
#pragma unroll
            for (int reg = 0; reg < 4; ++reg) {
                int row = rt * 16 + r4 + reg;
                float p0 = acc[rt][0][reg] + b3c0;
                float p1 = acc[rt][1][reg] + b3c1;
                float z0 = b2f(zs[row * 256 + wave * 32 + l15]);
                float z1 = b2f(zs[row * 256 + wave * 32 + 16 + l15]);
                float psq = p0 * p0 + p1 * p1;
                float zsq = z0 * z0 + z1 * z1;
                float pz  = p0 * z0 + p1 * z1;
#pragma unroll
                for (int o = 1; o < 16; o <<= 1) {
                    psq += __shfl_xor(psq, o);
                    zsq += __shfl_xor(zsq, o);
                    pz  += __shfl_xor(pz, o);
                }
                if (l15 == 0) {
                    rstat[row][wave][0] = psq;
                    rstat[row][wave][1] = zsq;
                    rstat[row][wave][2] = pz;
                }
            }
    }
    __syncthreads();

    // final per-row loss + block reduce (wave 0 only)
    if (tid < 64) {
        float a0 = 0.f, a1 = 0.f, a2 = 0.f;
        if (tid < 48) {
            float sp = 0.f, sz = 0.f, spz = 0.f;
#pragma unroll
            for (int w = 0; w < 8; ++w) {
                sp  += rstat[tid][w][0];
                sz  += rstat[tid][w][1];
                spz += rstat[tid][w][2];
            }
            float npn = sqrtf(sp), nzn = sqrtf(sz);
            float d = npn - 1.f;
            a2 = 0.02f * d * d;
            float mp = fmaxf(npn, 1e-8f), mz = fmaxf(nzn, 1e-8f);
            float lossr = (sp / (mp * mp) + sz / (mz * mz) - 2.f * spz / (mp * mz)) * (1.f / HH);
            float vm = vmask[tid];
            a0 = vm * lossr;
            a1 = vm;
        }
#pragma unroll
        for (int o = 1; o < 64; o <<= 1) {
            a0 += __shfl_xor(a0, o);
            a1 += __shfl_xor(a1, o);
            a2 += __shfl_xor(a2, o);
        }
        if (tid == 0) {
            part[blockIdx.x * 3 + 0] = a0;
            part[blockIdx.x * 3 + 1] = a1;
            part[blockIdx.x * 3 + 2] = a2;
        }
    }
}

// Final reduction over 256 partials.
__global__ void k_final(const float* __restrict__ part, float* out) {
    int tid = threadIdx.x, wave = tid >> 6, lane = tid & 63;
    float s0 = 0.f, s1 = 0.f, s2 = 0.f;
    for (int i = tid; i < 256; i += 256) {
        s0 += part[i * 3 + 0];
        s1 += part[i * 3 + 1];
        s2 += part[i * 3 + 2];
    }
    for (int o = 32; o; o >>= 1) {
        s0 += __shfl_xor(s0, o);
        s1 += __shfl_xor(s1, o);
        s2 += __shfl_xor(s2, o);
    }
    __shared__ float sm[4][3];
    if (lane == 0) { sm[wave][0] = s0; sm[wave][1] = s1; sm[wave][2] = s2; }
    __syncthreads();
    if (tid == 0) {
        float a = 0.f, b = 0.f, c = 0.f;
        for (int w = 0; w < 4; ++w) { a += sm[w][0]; b += sm[w][1]; c += sm[w][2]; }
        out[0] = a / fmaxf(b, 1.f) + c * (1.f / RR);
    }
}

extern "C" void kernel_launch(void* const* d_in, const int* in_sizes, int n_in,
                              void* d_out, int out_size, void* d_ws, size_t ws_size,
                              hipStream_t stream) {
    const int*   actions = (const int*)d_in[0];
    const float* dones   = (const float*)d_in[1];
    const float* b_t     = (const float*)d_in[2];
    const float* z_t     = (const float*)d_in[3];
    const int*   ts      = (const int*)d_in[4];
    const int*   us      = (const int*)d_in[5];
    const float* W_ih    = (const float*)d_in[6];
    const float* W_hh    = (const float*)d_in[7];
    const float* b_ih    = (const float*)d_in[8];
    const float* b_hh    = (const float*)d_in[9];
    const float* W1      = (const float*)d_in[10];
    const float* b1      = (const float*)d_in[11];
    const float* W2      = (const float*)d_in[12];
    const float* b2      = (const float*)d_in[13];
    const float* W3      = (const float*)d_in[14];
    const float* b3      = (const float*)d_in[15];

    char* ws = (char*)d_ws;
    int*            act   = (int*)(ws + OFF_ACT);
    unsigned short* hpred = (unsigned short*)(ws + OFF_HPRED);
    unsigned short* whh_s = (unsigned short*)(ws + OFF_WHH);
    unsigned short* w1t   = (unsigned short*)(ws + OFF_W1T);
    unsigned short* w2t   = (unsigned short*)(ws + OFF_W2T);
    unsigned short* w3t   = (unsigned short*)(ws + OFF_W3T);
    float*          tbl   = (float*)(ws + OFF_TBL);
    float*          part  = (float*)(ws + OFF_PART);

    // total prep elements: 196608+131072+262144+131072+14896+122880 = 858672
    k_prep<<<3355, 256, 0, stream>>>(W_hh, W1, W2, W3, W_ih, b_ih, b_hh, actions, ts,
                                     whh_s, w1t, w2t, w3t, tbl, act);
    k_gru_all<<<256, 512, 0, stream>>>(whh_s, tbl, b_hh, act, us, ts, b_t, hpred);
    k_mlp_loss<<<256, 512, 0, stream>>>(hpred, w1t, w2t, w3t, b1, b2, b3,
                                        z_t, dones, ts, us, part);
    k_final<<<1, 256, 0, stream>>>(part, (float*)d_out);
}